// Round 6
// baseline (218.727 us; speedup 1.0000x reference)
//
#include <hip/hip_runtime.h>
#include <math.h>
#include <limits.h>

#define HH 128
#define WW 128
#define HW (HH*WW)
#define BB 2
#define CC 14
#define NPAIR 26   // B * (C-1)
#define RPB 4                      // rows per k_C block
#define NBLK (NPAIR * (HH / RPB))  // 832 k_C blocks

typedef unsigned long long u64;

// ---------------------------------------------------------------------------
// ws layout (bytes):
//   cbP   : [NPAIR][WW] u64x2  @ 0        (53248)  fgP column masks (es & logit>0.5)
//   cbT   : [NPAIR][WW] u64x2  @ 53248    (53248)  fgT column masks (= teacher edge)
//   esC   : [NPAIR][WW] u64x2  @ 106496   (53248)  student edge column masks
//   flags : [NPAIR] int        @ 159744   (104)    bit0 anyFgP,1 anyBgP,2 anyFgT,3 anyBgT
//   sums  : [NPAIR] f32        @ 159872   (104)
//   done  : int                @ 160000   (4)      last-block ticket
// ---------------------------------------------------------------------------

// distance from row i to nearest set bit in 128-bit mask {lo,hi}; 255 if empty.
// i is wave-uniform in k_C -> uniform branches.
__device__ inline int nbd(u64 lo, u64 hi, int i) {
    int up = 255, down = 255;
    u64 slo, shi;
    if (i == 0)      { slo = lo; shi = hi; }
    else if (i < 64) { slo = (lo >> i) | (hi << (64 - i)); shi = hi >> i; }
    else             { slo = hi >> (i - 64); shi = 0ULL; }
    if (slo)      up = __builtin_ctzll(slo);
    else if (shi) up = 64 + __builtin_ctzll(shi);
    int s = 127 - i;
    u64 llo, lhi;
    if (s == 0)      { llo = lo; lhi = hi; }
    else if (s < 64) { lhi = (hi << s) | (lo >> (64 - s)); llo = lo << s; }
    else             { lhi = lo << (s - 64); llo = 0ULL; }
    if (lhi)      down = __builtin_clzll(lhi);
    else if (llo) down = 64 + __builtin_clzll(llo);
    return min(up, down);
}

__device__ inline u64 asm64(unsigned int (*p)[WW], int k0, int j) {
    return (u64)p[k0][j] | ((u64)p[k0 + 1][j] << 16)
         | ((u64)p[k0 + 2][j] << 32) | ((u64)p[k0 + 3][j] << 48);
}

// Fused per-pair seg + column bitmask build + bit-parallel edge masks.
// block = pair n; 1024 threads = (row-chunk k of 16 rows, column j).
// seg = (argmax == c), computed directly with the first-max tie rule:
//   L[c] > L[ch] for ch<c  AND  L[c] >= L[ch] for ch>c.
__global__ __launch_bounds__(1024) void k_prep(
        const float* __restrict__ Ls, const float* __restrict__ Lt,
        ulonglong2* __restrict__ cbP, ulonglong2* __restrict__ cbT,
        ulonglong2* __restrict__ esC, int* __restrict__ flags,
        float* __restrict__ sums, int* __restrict__ done) {
    int n = blockIdx.x;
    int tid = threadIdx.x;
    int k = tid >> 7;          // 0..7
    int j = tid & (WW - 1);
    int b = n / (CC - 1), c = 1 + (n - b * (CC - 1));
    if (tid == 0) { sums[n] = 0.0f; if (n == 0) *done = 0; }

    const float* S = Ls + (size_t)b * CC * HW;
    const float* T = Lt + (size_t)b * CC * HW;

    unsigned int s16 = 0, t16 = 0, h16 = 0;
    int i0 = k << 4;
#pragma unroll 4
    for (int r = 0; r < 16; ++r) {
        int off = (i0 + r) * WW + j;         // coalesced across j
        float vc = S[(size_t)c * HW + off];
        bool is = true;
#pragma unroll
        for (int ch = 0; ch < CC; ++ch) {
            if (ch == c) continue;
            float v = S[(size_t)ch * HW + off];
            is = is && (ch < c ? (vc > v) : (vc >= v));
        }
        float wc = T[(size_t)c * HW + off];
        bool it = true;
#pragma unroll
        for (int ch = 0; ch < CC; ++ch) {
            if (ch == c) continue;
            float v = T[(size_t)ch * HW + off];
            it = it && (ch < c ? (wc > v) : (wc >= v));
        }
        if (is)          s16 |= 1u << r;
        if (it)          t16 |= 1u << r;
        if (vc > 0.5f)   h16 |= 1u << r;
    }
    __shared__ unsigned int pS[8][WW], pT[8][WW], pH[8][WW];
    __shared__ int sfl[2];
    pS[k][j] = s16; pT[k][j] = t16; pH[k][j] = h16;
    __syncthreads();

    if (tid < WW) {
        u64 ms0 = asm64(pS, 0, j), ms1 = asm64(pS, 4, j);
        u64 mt0 = asm64(pT, 0, j), mt1 = asm64(pT, 4, j);
        u64 hi0 = asm64(pH, 0, j), hi1 = asm64(pH, 4, j);
        u64 Lsx = 0, Lsy = 0, Ltx = 0, Lty = 0, Rsx = 0, Rsy = 0, Rtx = 0, Rty = 0;
        if (j > 0)      { Lsx = asm64(pS, 0, j - 1); Lsy = asm64(pS, 4, j - 1);
                          Ltx = asm64(pT, 0, j - 1); Lty = asm64(pT, 4, j - 1); }
        if (j < WW - 1) { Rsx = asm64(pS, 0, j + 1); Rsy = asm64(pS, 4, j + 1);
                          Rtx = asm64(pT, 0, j + 1); Rty = asm64(pT, 4, j + 1); }

        // erosion: m & up & down & left & right; shifts insert 0 (border erodes)
        u64 U0 = ms0 << 1, U1 = (ms1 << 1) | (ms0 >> 63);
        u64 D0 = (ms0 >> 1) | (ms1 << 63), D1 = ms1 >> 1;
        u64 er0 = ms0 & U0 & D0 & Lsx & Rsx;
        u64 er1 = ms1 & U1 & D1 & Lsy & Rsy;
        u64 es0 = ms0 & ~er0, es1 = ms1 & ~er1;

        u64 Ut0 = mt0 << 1, Ut1 = (mt1 << 1) | (mt0 >> 63);
        u64 Dt0 = (mt0 >> 1) | (mt1 << 63), Dt1 = mt1 >> 1;
        u64 ert0 = mt0 & Ut0 & Dt0 & Ltx & Rtx;
        u64 ert1 = mt1 & Ut1 & Dt1 & Lty & Rty;
        u64 et0 = mt0 & ~ert0, et1 = mt1 & ~ert1;

        u64 fp0 = es0 & hi0, fp1 = es1 & hi1;   // pred = es*logit > 0.5

        int idx = n * WW + j;
        cbP[idx] = make_ulonglong2(fp0, fp1);
        cbT[idx] = make_ulonglong2(et0, et1);
        esC[idx] = make_ulonglong2(es0, es1);

        u64 bFgP = __ballot((fp0 | fp1) != 0ull);
        u64 bBgP = __ballot((fp0 & fp1) != ~0ull);
        u64 bFgT = __ballot((et0 | et1) != 0ull);
        u64 bBgT = __ballot((et0 & et1) != ~0ull);
        if ((tid & 63) == 0) {
            sfl[tid >> 6] = (bFgP ? 1 : 0) | (bBgP ? 2 : 0)
                          | (bFgT ? 4 : 0) | (bBgT ? 8 : 0);
        }
    }
    __syncthreads();
    if (tid == 0) flags[n] = sfl[0] | sfl[1];
}

// fused: column EDT (bit-trick) -> row EDT (early-exit expanding ring, uchar4
// d1 table) -> loss accumulation -> last-block final reduction.
// block = (pair n, 4-row tile), 512 threads = (r, j).
__global__ __launch_bounds__(512) void k_C(
        const float* __restrict__ Ls,
        const ulonglong2* __restrict__ cbP, const ulonglong2* __restrict__ cbT,
        const ulonglong2* __restrict__ esC,
        const int* __restrict__ flags, float* __restrict__ sums,
        int* __restrict__ done, float* __restrict__ out) {
    int n = blockIdx.x >> 5;          // pair
    int t = blockIdx.x & 31;          // row tile
    int r = threadIdx.x >> 7;         // 0..3 (wave-uniform)
    int j = threadIdx.x & (WW - 1);
    int i = t * RPB + r;
    int b = n / (CC - 1), c = 1 + (n - b * (CC - 1));

    int idx = n * WW + j;
    ulonglong2 mP = cbP[idx];
    ulonglong2 mT = cbT[idx];
    ulonglong2 eS = esC[idx];
    int f = flags[n];
    bool aP = (f & 3) == 3, aT = (f & 12) == 12;

    int dP  = nbd(mP.x, mP.y, i);
    int dPb = nbd(~mP.x, ~mP.y, i);
    int dT  = nbd(mT.x, mT.y, i);
    int dTb = nbd(~mT.x, ~mT.y, i);

    __shared__ uchar4 sq[RPB][WW];    // d1 per map (not squared; 255 sentinel)
    sq[r][j] = make_uchar4((unsigned char)dP, (unsigned char)dPb,
                           (unsigned char)dT, (unsigned char)dTb);
    __syncthreads();

    int bP = dP * dP, bPb = dPb * dPb, bT = dT * dT, bTb = dTb * dTb;
    int need = 0;
    if (aP) need = max(bP, bPb);
    if (aT) need = max(need, max(bT, bTb));
    // expanding ring: candidates at radius rad are >= rad^2, so once
    // rad^2 >= need (best over maps actually used), the min is final.
    for (int rad = 1; rad < WW; ++rad) {
        int rr = rad * rad;
        if (rr >= need) break;
        if (j >= rad) {
            uchar4 s = sq[r][j - rad];
            bP  = min(bP,  (int)s.x * s.x + rr); bPb = min(bPb, (int)s.y * s.y + rr);
            bT  = min(bT,  (int)s.z * s.z + rr); bTb = min(bTb, (int)s.w * s.w + rr);
        }
        if (j + rad < WW) {
            uchar4 s = sq[r][j + rad];
            bP  = min(bP,  (int)s.x * s.x + rr); bPb = min(bPb, (int)s.y * s.y + rr);
            bT  = min(bT,  (int)s.z * s.z + rr); bTb = min(bTb, (int)s.w * s.w + rr);
        }
        need = 0;
        if (aP) need = max(bP, bPb);
        if (aT) need = max(need, max(bT, bTb));
    }

    float fieldP = aP ? (float)(bP + bPb) : 0.0f;
    float fieldT = aT ? (float)(bT + bTb) : 0.0f;

    bool es = ((i < 64 ? (eS.x >> i) : (eS.y >> (i - 64))) & 1ull) != 0;
    bool et = ((i < 64 ? (mT.x >> i) : (mT.y >> (i - 64))) & 1ull) != 0;
    float lv = Ls[(size_t)(b * CC + c) * HW + i * WW + j];  // coalesced
    float predv = es ? lv : 0.0f;
    float targv = et ? (float)c : 0.0f;
    float diff = predv - targv;
    float v = diff * diff * (fieldP + fieldT);

    for (int o = 32; o > 0; o >>= 1) v += __shfl_down(v, o);
    __shared__ float wsum[8];
    __shared__ int won;
    int lane = threadIdx.x & 63, w = threadIdx.x >> 6;
    if (lane == 0) wsum[w] = v;
    if (threadIdx.x == 0) won = 0;
    __syncthreads();
    if (threadIdx.x == 0) {
        float tot = 0.0f;
#pragma unroll
        for (int q = 0; q < 8; ++q) tot += wsum[q];
        atomicAdd(&sums[n], tot);
        __threadfence();                       // sums visible before ticket
        if (atomicAdd(done, 1) == NBLK - 1) won = 1;
    }
    __syncthreads();
    if (won && threadIdx.x < 64) {             // wave 0 of the last block
        float vv = 0.0f;
        if (threadIdx.x < NPAIR) {
            float hd = atomicAdd(&sums[threadIdx.x], 0.0f) * (1.0f / (float)HW);
            vv = logf(hd + 1.0f);
        }
        for (int o = 32; o > 0; o >>= 1) vv += __shfl_down(vv, o);
        if (threadIdx.x == 0) out[0] = 0.5f * vv;   // (1 - LOSS_WEIGHT) * sum
    }
}

extern "C" void kernel_launch(void* const* d_in, const int* in_sizes, int n_in,
                              void* d_out, int out_size, void* d_ws, size_t ws_size,
                              hipStream_t stream) {
    const float* Ls = (const float*)d_in[0];
    const float* Lt = (const float*)d_in[1];
    float* out = (float*)d_out;

    char* w = (char*)d_ws;
    ulonglong2*    cbP   = (ulonglong2*)(w);
    ulonglong2*    cbT   = (ulonglong2*)(w + 53248);
    ulonglong2*    esC   = (ulonglong2*)(w + 106496);
    int*           flags = (int*)       (w + 159744);
    float*         sums  = (float*)     (w + 159872);
    int*           done  = (int*)       (w + 160000);

    k_prep<<<NPAIR, 1024, 0, stream>>>(Ls, Lt, cbP, cbT, esC, flags, sums, done);
    k_C<<<NBLK, 512, 0, stream>>>(Ls, cbP, cbT, esC, flags, sums, done, out);
}

// Round 7
// 73.239 us; speedup vs baseline: 2.9865x; 2.9865x over previous
//
#include <hip/hip_runtime.h>
#include <math.h>
#include <limits.h>

#define HH 128
#define WW 128
#define HW (HH*WW)
#define BB 2
#define CC 14
#define NPAIR 26   // B * (C-1)
#define RPB 8                      // rows per k_C block
#define NBLK (NPAIR * (HH / RPB))  // 416 k_C blocks

typedef unsigned long long u64;

// ---------------------------------------------------------------------------
// ws layout (bytes):
//   ps    : [BB][HW] u8        @ 0        (32768)
//   pt    : [BB][HW] u8        @ 32768    (32768)
//   cbP   : [NPAIR][WW] u64x2  @ 65536    (53248)  fgP column masks (es & logit>0.5)
//   cbT   : [NPAIR][WW] u64x2  @ 118784   (53248)  fgT column masks (= teacher edge)
//   esC   : [NPAIR][WW] u64x2  @ 172032   (53248)  student edge column masks
//   flags : [NPAIR] int        @ 225280   (104)    bit0 anyFgP,1 anyBgP,2 anyFgT,3 anyBgT
//   sums  : [NPAIR] f32        @ 225408   (104)
//   done  : int                @ 225536   (4)      last-block ticket
// ---------------------------------------------------------------------------

// distance from row i to nearest set bit in 128-bit mask {lo,hi}; 255 if empty.
// i is wave-uniform in k_C -> uniform branches.
__device__ inline int nbd(u64 lo, u64 hi, int i) {
    int up = 255, down = 255;
    u64 slo, shi;
    if (i == 0)      { slo = lo; shi = hi; }
    else if (i < 64) { slo = (lo >> i) | (hi << (64 - i)); shi = hi >> i; }
    else             { slo = hi >> (i - 64); shi = 0ULL; }
    if (slo)      up = __builtin_ctzll(slo);
    else if (shi) up = 64 + __builtin_ctzll(shi);
    int s = 127 - i;
    u64 llo, lhi;
    if (s == 0)      { llo = lo; lhi = hi; }
    else if (s < 64) { lhi = (hi << s) | (lo >> (64 - s)); llo = lo << s; }
    else             { lhi = lo << (s - 64); llo = 0ULL; }
    if (lhi)      down = __builtin_clzll(lhi);
    else if (llo) down = 64 + __builtin_clzll(llo);
    return min(up, down);
}

// argmax over channels, 4 pixels/thread (float4). block 0 zeroes flags/sums/done.
__global__ void k_argmax(const float* __restrict__ Ls, const float* __restrict__ Lt,
                         unsigned char* __restrict__ ps, unsigned char* __restrict__ pt,
                         int* __restrict__ flags, float* __restrict__ sums,
                         int* __restrict__ done) {
    if (blockIdx.x == 0) {
        if (threadIdx.x < NPAIR) { flags[threadIdx.x] = 0; sums[threadIdx.x] = 0.0f; }
        if (threadIdx.x == 0) *done = 0;
    }
    int tid = blockIdx.x * blockDim.x + threadIdx.x;
    const int total4 = BB * HW / 4;
    if (tid >= 2 * total4) return;
    const float* L; unsigned char* dst; int p4;
    if (tid < total4) { L = Ls; dst = ps; p4 = tid; }
    else              { L = Lt; dst = pt; p4 = tid - total4; }
    int b = p4 / (HW / 4);
    int q4 = p4 - b * (HW / 4);
    const float4* base = (const float4*)(L + (size_t)b * CC * HW) + q4;
    float4 best = base[0];
    uchar4 bi = make_uchar4(0, 0, 0, 0);
#pragma unroll
    for (int c = 1; c < CC; ++c) {
        float4 v = base[(size_t)c * (HW / 4)];
        if (v.x > best.x) { best.x = v.x; bi.x = (unsigned char)c; }
        if (v.y > best.y) { best.y = v.y; bi.y = (unsigned char)c; }
        if (v.z > best.z) { best.z = v.z; bi.z = (unsigned char)c; }
        if (v.w > best.w) { best.w = v.w; bi.w = (unsigned char)c; }
    }
    ((uchar4*)dst)[b * (HW / 4) + q4] = bi;
}

__device__ inline u64 asm64(unsigned int (*p)[WW], int k0, int j) {
    return (u64)p[k0][j] | ((u64)p[k0 + 1][j] << 16)
         | ((u64)p[k0 + 2][j] << 32) | ((u64)p[k0 + 3][j] << 48);
}

// per-pair column bitmask build + bit-parallel edge masks.
// block = pair n; 1024 threads = (row-chunk k of 16 rows, column j).
__global__ __launch_bounds__(1024) void k_prep(
        const unsigned char* __restrict__ ps, const unsigned char* __restrict__ pt,
        const float* __restrict__ Ls,
        ulonglong2* __restrict__ cbP, ulonglong2* __restrict__ cbT,
        ulonglong2* __restrict__ esC, int* __restrict__ flags) {
    int n = blockIdx.x;
    int tid = threadIdx.x;
    int k = tid >> 7;          // 0..7
    int j = tid & (WW - 1);
    int b = n / (CC - 1), c = 1 + (n - b * (CC - 1));
    const unsigned char* P = ps + b * HW;
    const unsigned char* T = pt + b * HW;
    const float* Lp = Ls + (size_t)(b * CC + c) * HW;

    unsigned int s16 = 0, t16 = 0, h16 = 0;
    int i0 = k << 4;
#pragma unroll
    for (int r = 0; r < 16; ++r) {
        int off = (i0 + r) * WW + j;         // coalesced across j
        if (P[off] == c)      s16 |= 1u << r;
        if (T[off] == c)      t16 |= 1u << r;
        if (Lp[off] > 0.5f)   h16 |= 1u << r;
    }
    __shared__ unsigned int pS[8][WW], pT[8][WW], pH[8][WW];
    pS[k][j] = s16; pT[k][j] = t16; pH[k][j] = h16;
    __syncthreads();

    if (tid < WW) {
        u64 ms0 = asm64(pS, 0, j), ms1 = asm64(pS, 4, j);
        u64 mt0 = asm64(pT, 0, j), mt1 = asm64(pT, 4, j);
        u64 hi0 = asm64(pH, 0, j), hi1 = asm64(pH, 4, j);
        u64 Lsx = 0, Lsy = 0, Ltx = 0, Lty = 0, Rsx = 0, Rsy = 0, Rtx = 0, Rty = 0;
        if (j > 0)      { Lsx = asm64(pS, 0, j - 1); Lsy = asm64(pS, 4, j - 1);
                          Ltx = asm64(pT, 0, j - 1); Lty = asm64(pT, 4, j - 1); }
        if (j < WW - 1) { Rsx = asm64(pS, 0, j + 1); Rsy = asm64(pS, 4, j + 1);
                          Rtx = asm64(pT, 0, j + 1); Rty = asm64(pT, 4, j + 1); }

        // erosion: m & up & down & left & right; shifts insert 0 (border erodes)
        u64 U0 = ms0 << 1, U1 = (ms1 << 1) | (ms0 >> 63);
        u64 D0 = (ms0 >> 1) | (ms1 << 63), D1 = ms1 >> 1;
        u64 er0 = ms0 & U0 & D0 & Lsx & Rsx;
        u64 er1 = ms1 & U1 & D1 & Lsy & Rsy;
        u64 es0 = ms0 & ~er0, es1 = ms1 & ~er1;

        u64 Ut0 = mt0 << 1, Ut1 = (mt1 << 1) | (mt0 >> 63);
        u64 Dt0 = (mt0 >> 1) | (mt1 << 63), Dt1 = mt1 >> 1;
        u64 ert0 = mt0 & Ut0 & Dt0 & Ltx & Rtx;
        u64 ert1 = mt1 & Ut1 & Dt1 & Lty & Rty;
        u64 et0 = mt0 & ~ert0, et1 = mt1 & ~ert1;

        u64 fp0 = es0 & hi0, fp1 = es1 & hi1;   // pred = es*logit > 0.5

        int idx = n * WW + j;
        cbP[idx] = make_ulonglong2(fp0, fp1);
        cbT[idx] = make_ulonglong2(et0, et1);
        esC[idx] = make_ulonglong2(es0, es1);

        u64 bFgP = __ballot((fp0 | fp1) != 0ull);
        u64 bBgP = __ballot((fp0 & fp1) != ~0ull);
        u64 bFgT = __ballot((et0 | et1) != 0ull);
        u64 bBgT = __ballot((et0 & et1) != ~0ull);
        if ((j & 63) == 0) {
            int fl = (bFgP ? 1 : 0) | (bBgP ? 2 : 0) | (bFgT ? 4 : 0) | (bBgT ? 8 : 0);
            atomicOr(&flags[n], fl);
        }
    }
}

// fused: column EDT (bit-trick) -> row EDT (early-exit expanding ring) ->
// loss accumulation -> last-block final reduction.
// block = (pair n, 8-row tile), 1024 threads = (r, j).
__global__ __launch_bounds__(1024) void k_C(
        const float* __restrict__ Ls,
        const ulonglong2* __restrict__ cbP, const ulonglong2* __restrict__ cbT,
        const ulonglong2* __restrict__ esC,
        const int* __restrict__ flags, float* __restrict__ sums,
        int* __restrict__ done, float* __restrict__ out) {
    int n = blockIdx.x >> 4;          // pair
    int t = blockIdx.x & 15;          // row tile
    int r = threadIdx.x >> 7;         // 0..7 (wave-uniform)
    int j = threadIdx.x & (WW - 1);
    int i = t * RPB + r;
    int b = n / (CC - 1), c = 1 + (n - b * (CC - 1));

    int idx = n * WW + j;
    ulonglong2 mP = cbP[idx];
    ulonglong2 mT = cbT[idx];
    ulonglong2 eS = esC[idx];
    float lv = Ls[(size_t)(b * CC + c) * HW + i * WW + j];  // hoisted, coalesced
    int f = flags[n];
    bool aP = (f & 3) == 3, aT = (f & 12) == 12;

    int dP  = nbd(mP.x, mP.y, i);
    int dPb = nbd(~mP.x, ~mP.y, i);
    int dT  = nbd(mT.x, mT.y, i);
    int dTb = nbd(~mT.x, ~mT.y, i);

    __shared__ uchar4 sq[RPB][WW];    // d1 per map (255 sentinel; squared on read)
    sq[r][j] = make_uchar4((unsigned char)dP, (unsigned char)dPb,
                           (unsigned char)dT, (unsigned char)dTb);
    __syncthreads();

    int bP = dP * dP, bPb = dPb * dPb, bT = dT * dT, bTb = dTb * dTb;
    int need = 0;
    if (aP) need = max(bP, bPb);
    if (aT) need = max(need, max(bT, bTb));
    // expanding ring: candidates at radius rad are >= rad^2, so once
    // rad^2 >= need (best over maps actually used), the min is final.
    for (int rad = 1; rad < WW; ++rad) {
        int rr = rad * rad;
        if (rr >= need) break;
        if (j >= rad) {
            uchar4 s = sq[r][j - rad];
            bP  = min(bP,  (int)s.x * s.x + rr); bPb = min(bPb, (int)s.y * s.y + rr);
            bT  = min(bT,  (int)s.z * s.z + rr); bTb = min(bTb, (int)s.w * s.w + rr);
        }
        if (j + rad < WW) {
            uchar4 s = sq[r][j + rad];
            bP  = min(bP,  (int)s.x * s.x + rr); bPb = min(bPb, (int)s.y * s.y + rr);
            bT  = min(bT,  (int)s.z * s.z + rr); bTb = min(bTb, (int)s.w * s.w + rr);
        }
        need = 0;
        if (aP) need = max(bP, bPb);
        if (aT) need = max(need, max(bT, bTb));
    }

    float fieldP = aP ? (float)(bP + bPb) : 0.0f;
    float fieldT = aT ? (float)(bT + bTb) : 0.0f;

    bool es = ((i < 64 ? (eS.x >> i) : (eS.y >> (i - 64))) & 1ull) != 0;
    bool et = ((i < 64 ? (mT.x >> i) : (mT.y >> (i - 64))) & 1ull) != 0;
    float predv = es ? lv : 0.0f;
    float targv = et ? (float)c : 0.0f;
    float diff = predv - targv;
    float v = diff * diff * (fieldP + fieldT);

    for (int o = 32; o > 0; o >>= 1) v += __shfl_down(v, o);
    __shared__ float wsum[16];
    __shared__ int won;
    int lane = threadIdx.x & 63, w = threadIdx.x >> 6;
    if (lane == 0) wsum[w] = v;
    if (threadIdx.x == 0) won = 0;
    __syncthreads();
    if (threadIdx.x == 0) {
        float tot = 0.0f;
#pragma unroll
        for (int q = 0; q < 16; ++q) tot += wsum[q];
        atomicAdd(&sums[n], tot);
        __threadfence();                       // sums visible before ticket
        if (atomicAdd(done, 1) == NBLK - 1) won = 1;
    }
    __syncthreads();
    if (won && threadIdx.x < 64) {             // wave 0 of the last block
        float vv = 0.0f;
        if (threadIdx.x < NPAIR) {
            float hd = atomicAdd(&sums[threadIdx.x], 0.0f) * (1.0f / (float)HW);
            vv = logf(hd + 1.0f);
        }
        for (int o = 32; o > 0; o >>= 1) vv += __shfl_down(vv, o);
        if (threadIdx.x == 0) out[0] = 0.5f * vv;   // (1 - LOSS_WEIGHT) * sum
    }
}

extern "C" void kernel_launch(void* const* d_in, const int* in_sizes, int n_in,
                              void* d_out, int out_size, void* d_ws, size_t ws_size,
                              hipStream_t stream) {
    const float* Ls = (const float*)d_in[0];
    const float* Lt = (const float*)d_in[1];
    float* out = (float*)d_out;

    char* w = (char*)d_ws;
    unsigned char* ps    = (unsigned char*)(w);
    unsigned char* pt    = (unsigned char*)(w + 32768);
    ulonglong2*    cbP   = (ulonglong2*)   (w + 65536);
    ulonglong2*    cbT   = (ulonglong2*)   (w + 118784);
    ulonglong2*    esC   = (ulonglong2*)   (w + 172032);
    int*           flags = (int*)          (w + 225280);
    float*         sums  = (float*)        (w + 225408);
    int*           done  = (int*)          (w + 225536);

    k_argmax<<<(2 * BB * HW / 4 + 255) / 256, 256, 0, stream>>>(Ls, Lt, ps, pt, flags, sums, done);
    k_prep<<<NPAIR, 1024, 0, stream>>>(ps, pt, Ls, cbP, cbT, esC, flags);
    k_C<<<NBLK, 1024, 0, stream>>>(Ls, cbP, cbT, esC, flags, sums, done, out);
}

// Round 8
// 72.397 us; speedup vs baseline: 3.0212x; 1.0116x over previous
//
#include <hip/hip_runtime.h>
#include <math.h>
#include <limits.h>

#define HH 128
#define WW 128
#define HW (HH*WW)
#define BB 2
#define CC 14
#define NPAIR 26   // B * (C-1)
#define RPB 8                      // rows per k_C block
#define NBLK (NPAIR * (HH / RPB))  // 416 k_C blocks

typedef unsigned long long u64;

// ---------------------------------------------------------------------------
// ws layout (bytes):
//   ps    : [BB][HW] u8  @ 0      (32768)   student argmax labels
//   pt    : [BB][HW] u8  @ 32768  (32768)   teacher argmax labels
//   sums  : [NPAIR] f32  @ 65536  (104)
//   done  : int          @ 65664  (4)       last-block ticket
// ---------------------------------------------------------------------------

// distance from row i to nearest set bit in 128-bit mask {lo,hi}; 255 if empty.
// i is wave-uniform in k_C -> uniform branches.
__device__ inline int nbd(u64 lo, u64 hi, int i) {
    int up = 255, down = 255;
    u64 slo, shi;
    if (i == 0)      { slo = lo; shi = hi; }
    else if (i < 64) { slo = (lo >> i) | (hi << (64 - i)); shi = hi >> i; }
    else             { slo = hi >> (i - 64); shi = 0ULL; }
    if (slo)      up = __builtin_ctzll(slo);
    else if (shi) up = 64 + __builtin_ctzll(shi);
    int s = 127 - i;
    u64 llo, lhi;
    if (s == 0)      { llo = lo; lhi = hi; }
    else if (s < 64) { lhi = (hi << s) | (lo >> (64 - s)); llo = lo << s; }
    else             { lhi = lo << (s - 64); llo = 0ULL; }
    if (lhi)      down = __builtin_clzll(lhi);
    else if (llo) down = 64 + __builtin_clzll(llo);
    return min(up, down);
}

// argmax over channels, 4 pixels/thread (float4). block 0 zeroes sums/done.
__global__ void k_argmax(const float* __restrict__ Ls, const float* __restrict__ Lt,
                         unsigned char* __restrict__ ps, unsigned char* __restrict__ pt,
                         float* __restrict__ sums, int* __restrict__ done) {
    if (blockIdx.x == 0) {
        if (threadIdx.x < NPAIR) sums[threadIdx.x] = 0.0f;
        if (threadIdx.x == 0) *done = 0;
    }
    int tid = blockIdx.x * blockDim.x + threadIdx.x;
    const int total4 = BB * HW / 4;
    if (tid >= 2 * total4) return;
    const float* L; unsigned char* dst; int p4;
    if (tid < total4) { L = Ls; dst = ps; p4 = tid; }
    else              { L = Lt; dst = pt; p4 = tid - total4; }
    int b = p4 / (HW / 4);
    int q4 = p4 - b * (HW / 4);
    const float4* base = (const float4*)(L + (size_t)b * CC * HW) + q4;
    float4 best = base[0];
    uchar4 bi = make_uchar4(0, 0, 0, 0);
#pragma unroll
    for (int c = 1; c < CC; ++c) {
        float4 v = base[(size_t)c * (HW / 4)];
        if (v.x > best.x) { best.x = v.x; bi.x = (unsigned char)c; }
        if (v.y > best.y) { best.y = v.y; bi.y = (unsigned char)c; }
        if (v.z > best.z) { best.z = v.z; bi.z = (unsigned char)c; }
        if (v.w > best.w) { best.w = v.w; bi.w = (unsigned char)c; }
    }
    ((uchar4*)dst)[b * (HW / 4) + q4] = bi;
}

__device__ inline u64 asm64(unsigned int (*p)[WW], int k0, int j) {
    return (u64)p[k0][j] | ((u64)p[k0 + 1][j] << 16)
         | ((u64)p[k0 + 2][j] << 32) | ((u64)p[k0 + 3][j] << 48);
}

// One fused kernel per (pair, 8-row tile):
//   phase 1: column bitmask build (16-row chunks per thread, coalesced)
//   phase 2: bit-parallel erosion/edge -> per-column masks in LDS (+ flags)
//   phase 3: column EDT (bit-trick) -> row EDT (early-exit expanding ring)
//            -> loss accumulation -> last-block final reduction.
// block = (pair n, row tile t), 1024 threads = (chunk k / row r, column j).
__global__ __launch_bounds__(1024) void k_C(
        const unsigned char* __restrict__ ps, const unsigned char* __restrict__ pt,
        const float* __restrict__ Ls,
        float* __restrict__ sums, int* __restrict__ done, float* __restrict__ out) {
    int n = blockIdx.x >> 4;          // pair
    int t = blockIdx.x & 15;          // row tile
    int tid = threadIdx.x;
    int k = tid >> 7;                 // 0..7 (chunk in ph1, row r in ph3)
    int j = tid & (WW - 1);
    int b = n / (CC - 1), c = 1 + (n - b * (CC - 1));
    const unsigned char* P = ps + b * HW;
    const unsigned char* T = pt + b * HW;
    const float* Lp = Ls + (size_t)(b * CC + c) * HW;

    int i = t * RPB + k;              // this thread's output row (phase 3)
    float lv = Lp[i * WW + j];        // hoisted, coalesced, independent

    // ---- phase 1: 16-row chunk bitmasks (coalesced across j) ----
    unsigned int s16 = 0, t16 = 0, h16 = 0;
    int i0 = k << 4;
#pragma unroll
    for (int r = 0; r < 16; ++r) {
        int off = (i0 + r) * WW + j;
        if (P[off] == c)              s16 |= 1u << r;
        if (T[off] == c)              t16 |= 1u << r;
        if (Lp[off] > 0.5f)           h16 |= 1u << r;
    }
    __shared__ unsigned int pS[8][WW], pT[8][WW], pH[8][WW];
    pS[k][j] = s16; pT[k][j] = t16; pH[k][j] = h16;
    __syncthreads();

    // ---- phase 2: erosion/edge bit-math, 128 threads ----
    __shared__ ulonglong2 colFP[WW], colET[WW], colES[WW];
    __shared__ int sfl[2];
    if (tid < WW) {
        u64 ms0 = asm64(pS, 0, j), ms1 = asm64(pS, 4, j);
        u64 mt0 = asm64(pT, 0, j), mt1 = asm64(pT, 4, j);
        u64 hi0 = asm64(pH, 0, j), hi1 = asm64(pH, 4, j);
        u64 Lsx = 0, Lsy = 0, Ltx = 0, Lty = 0, Rsx = 0, Rsy = 0, Rtx = 0, Rty = 0;
        if (j > 0)      { Lsx = asm64(pS, 0, j - 1); Lsy = asm64(pS, 4, j - 1);
                          Ltx = asm64(pT, 0, j - 1); Lty = asm64(pT, 4, j - 1); }
        if (j < WW - 1) { Rsx = asm64(pS, 0, j + 1); Rsy = asm64(pS, 4, j + 1);
                          Rtx = asm64(pT, 0, j + 1); Rty = asm64(pT, 4, j + 1); }

        // erosion: m & up & down & left & right; shifts insert 0 (border erodes)
        u64 U0 = ms0 << 1, U1 = (ms1 << 1) | (ms0 >> 63);
        u64 D0 = (ms0 >> 1) | (ms1 << 63), D1 = ms1 >> 1;
        u64 er0 = ms0 & U0 & D0 & Lsx & Rsx;
        u64 er1 = ms1 & U1 & D1 & Lsy & Rsy;
        u64 es0 = ms0 & ~er0, es1 = ms1 & ~er1;

        u64 Ut0 = mt0 << 1, Ut1 = (mt1 << 1) | (mt0 >> 63);
        u64 Dt0 = (mt0 >> 1) | (mt1 << 63), Dt1 = mt1 >> 1;
        u64 ert0 = mt0 & Ut0 & Dt0 & Ltx & Rtx;
        u64 ert1 = mt1 & Ut1 & Dt1 & Lty & Rty;
        u64 et0 = mt0 & ~ert0, et1 = mt1 & ~ert1;

        u64 fp0 = es0 & hi0, fp1 = es1 & hi1;   // pred = es*logit > 0.5

        colFP[j] = make_ulonglong2(fp0, fp1);
        colET[j] = make_ulonglong2(et0, et1);
        colES[j] = make_ulonglong2(es0, es1);

        u64 bFgP = __ballot((fp0 | fp1) != 0ull);
        u64 bBgP = __ballot((fp0 & fp1) != ~0ull);
        u64 bFgT = __ballot((et0 | et1) != 0ull);
        u64 bBgT = __ballot((et0 & et1) != ~0ull);
        if ((tid & 63) == 0) {
            sfl[tid >> 6] = (bFgP ? 1 : 0) | (bBgP ? 2 : 0)
                          | (bFgT ? 4 : 0) | (bBgT ? 8 : 0);
        }
    }
    __syncthreads();

    // ---- phase 3: column EDT + expanding-ring row EDT + loss ----
    ulonglong2 mP = colFP[j];
    ulonglong2 mT = colET[j];
    ulonglong2 eS = colES[j];
    int f = sfl[0] | sfl[1];
    bool aP = (f & 3) == 3, aT = (f & 12) == 12;

    int dP  = nbd(mP.x, mP.y, i);
    int dPb = nbd(~mP.x, ~mP.y, i);
    int dT  = nbd(mT.x, mT.y, i);
    int dTb = nbd(~mT.x, ~mT.y, i);

    __shared__ uchar4 sq[RPB][WW];    // d1 per map (255 sentinel; squared on read)
    sq[k][j] = make_uchar4((unsigned char)dP, (unsigned char)dPb,
                           (unsigned char)dT, (unsigned char)dTb);
    __syncthreads();

    int bP = dP * dP, bPb = dPb * dPb, bT = dT * dT, bTb = dTb * dTb;
    int need = 0;
    if (aP) need = max(bP, bPb);
    if (aT) need = max(need, max(bT, bTb));
    // expanding ring: candidates at radius rad are >= rad^2, so once
    // rad^2 >= need (best over maps actually used), the min is final.
    for (int rad = 1; rad < WW; ++rad) {
        int rr = rad * rad;
        if (rr >= need) break;
        if (j >= rad) {
            uchar4 s = sq[k][j - rad];
            bP  = min(bP,  (int)s.x * s.x + rr); bPb = min(bPb, (int)s.y * s.y + rr);
            bT  = min(bT,  (int)s.z * s.z + rr); bTb = min(bTb, (int)s.w * s.w + rr);
        }
        if (j + rad < WW) {
            uchar4 s = sq[k][j + rad];
            bP  = min(bP,  (int)s.x * s.x + rr); bPb = min(bPb, (int)s.y * s.y + rr);
            bT  = min(bT,  (int)s.z * s.z + rr); bTb = min(bTb, (int)s.w * s.w + rr);
        }
        need = 0;
        if (aP) need = max(bP, bPb);
        if (aT) need = max(need, max(bT, bTb));
    }

    float fieldP = aP ? (float)(bP + bPb) : 0.0f;
    float fieldT = aT ? (float)(bT + bTb) : 0.0f;

    bool es = ((i < 64 ? (eS.x >> i) : (eS.y >> (i - 64))) & 1ull) != 0;
    bool et = ((i < 64 ? (mT.x >> i) : (mT.y >> (i - 64))) & 1ull) != 0;
    float predv = es ? lv : 0.0f;
    float targv = et ? (float)c : 0.0f;
    float diff = predv - targv;
    float v = diff * diff * (fieldP + fieldT);

    for (int o = 32; o > 0; o >>= 1) v += __shfl_down(v, o);
    __shared__ float wsum[16];
    __shared__ int won;
    int lane = threadIdx.x & 63, w = threadIdx.x >> 6;
    if (lane == 0) wsum[w] = v;
    if (threadIdx.x == 0) won = 0;
    __syncthreads();
    if (threadIdx.x == 0) {
        float tot = 0.0f;
#pragma unroll
        for (int q = 0; q < 16; ++q) tot += wsum[q];
        atomicAdd(&sums[n], tot);
        __threadfence();                       // sums visible before ticket
        if (atomicAdd(done, 1) == NBLK - 1) won = 1;
    }
    __syncthreads();
    if (won && threadIdx.x < 64) {             // wave 0 of the last block
        float vv = 0.0f;
        if (threadIdx.x < NPAIR) {
            float hd = atomicAdd(&sums[threadIdx.x], 0.0f) * (1.0f / (float)HW);
            vv = logf(hd + 1.0f);
        }
        for (int o = 32; o > 0; o >>= 1) vv += __shfl_down(vv, o);
        if (threadIdx.x == 0) out[0] = 0.5f * vv;   // (1 - LOSS_WEIGHT) * sum
    }
}

extern "C" void kernel_launch(void* const* d_in, const int* in_sizes, int n_in,
                              void* d_out, int out_size, void* d_ws, size_t ws_size,
                              hipStream_t stream) {
    const float* Ls = (const float*)d_in[0];
    const float* Lt = (const float*)d_in[1];
    float* out = (float*)d_out;

    char* w = (char*)d_ws;
    unsigned char* ps   = (unsigned char*)(w);
    unsigned char* pt   = (unsigned char*)(w + 32768);
    float*         sums = (float*)        (w + 65536);
    int*           done = (int*)          (w + 65664);

    k_argmax<<<(2 * BB * HW / 4 + 255) / 256, 256, 0, stream>>>(Ls, Lt, ps, pt, sums, done);
    k_C<<<NBLK, 1024, 0, stream>>>(ps, pt, Ls, sums, done, out);
}